// Round 8
// baseline (4002.868 us; speedup 1.0000x reference)
//
#include <hip/hip_runtime.h>
#include <math.h>

#define NVV 100000
#define NCC 420000
#define EE  630000
#define HH  128
#define LL  8

typedef unsigned int uint;
typedef unsigned short ushort;
typedef __attribute__((ext_vector_type(8))) short bf16x8;
typedef __attribute__((ext_vector_type(4))) float f32x4;

#define MFMA16(a,b,c) __builtin_amdgcn_mfma_f32_16x16x32_bf16(a,b,c,0,0,0)
// swizzled ushort index within a [128 rows][128 cols-of-bf16] LDS tile
#define SW(r,k) (((r)<<7) + ((k) ^ (((r)&7)<<3)))

// ---------------- bf16 helpers (bit-level, RNE) ----------------
__device__ inline float bf2f(uint u){ return __uint_as_float(u << 16); }
__device__ inline uint  f2bf(float f){
  uint b = __float_as_uint(f);
  return (b + 0x7FFFu + ((b >> 16) & 1u)) >> 16;
}
__device__ inline uint pack2(float a, float b){ return f2bf(a) | (f2bf(b) << 16); }
__device__ inline float4 relu4(float4 v){
  v.x = fmaxf(v.x, 0.f); v.y = fmaxf(v.y, 0.f);
  v.z = fmaxf(v.z, 0.f); v.w = fmaxf(v.w, 0.f);
  return v;
}

__global__ void k_sentinel(float* out, float v){
  if (blockIdx.x == 0 && threadIdx.x == 0) out[0] = v;
}

// ---------------- embeddings ----------------
__device__ inline float4 vemb4(const float* __restrict__ xv, const float* __restrict__ W,
                               const float* __restrict__ b, int i, int h4){
  float x0 = xv[4*i+0], x1 = xv[4*i+1], x2 = xv[4*i+2], x3 = xv[4*i+3];
  float4 w0 = *(const float4*)(W + 0*HH + h4);
  float4 w1 = *(const float4*)(W + 1*HH + h4);
  float4 w2 = *(const float4*)(W + 2*HH + h4);
  float4 w3 = *(const float4*)(W + 3*HH + h4);
  float4 bb = *(const float4*)(b + h4);
  float4 r;
  r.x = fmaf(x0,w0.x, fmaf(x1,w1.x, fmaf(x2,w2.x, fmaf(x3,w3.x, bb.x))));
  r.y = fmaf(x0,w0.y, fmaf(x1,w1.y, fmaf(x2,w2.y, fmaf(x3,w3.y, bb.y))));
  r.z = fmaf(x0,w0.z, fmaf(x1,w1.z, fmaf(x2,w2.z, fmaf(x3,w3.z, bb.z))));
  r.w = fmaf(x0,w0.w, fmaf(x1,w1.w, fmaf(x2,w2.w, fmaf(x3,w3.w, bb.w))));
  return r;
}

__global__ void k_embed_v(const float* __restrict__ xv, const float* __restrict__ W,
                          const float* __restrict__ b, float* __restrict__ out){
  int tid = blockIdx.x * 256 + threadIdx.x;
  int i = tid >> 5;
  if (i >= NVV) return;
  int h4 = (tid & 31) << 2;
  *(float4*)(out + (size_t)i*HH + h4) = relu4(vemb4(xv, W, b, i, h4));
}

__global__ void k_embed_c(const float* __restrict__ xc, const float* __restrict__ W,
                          const float* __restrict__ b, uint* __restrict__ out){
  int tid = blockIdx.x * 256 + threadIdx.x;
  int i = tid >> 5;
  if (i >= NCC) return;
  int c2 = tid & 31;
  int h4 = c2 << 2;
  float x0 = xc[i];
  float4 w = *(const float4*)(W + h4);
  float4 bb = *(const float4*)(b + h4);
  float4 r;
  r.x = fmaxf(fmaf(x0, w.x, bb.x), 0.f);
  r.y = fmaxf(fmaf(x0, w.y, bb.y), 0.f);
  r.z = fmaxf(fmaf(x0, w.z, bb.z), 0.f);
  r.w = fmaxf(fmaf(x0, w.w, bb.w), 0.f);
  uint2 o; o.x = pack2(r.x, r.y); o.y = pack2(r.z, r.w);
  *(uint2*)(out + (size_t)i*64 + c2*2) = o;
}

// ---------------- weight prep: transpose + swizzle + hi/lo split ----------------
// wt layout: [mat 0..6][layer 0..7][hi/lo][16384 ushorts], element (n,k) at SW(n,k)
// mats: 0 Wl_pos, 1 Wl_neg, 2 Wl_rpos, 3 Wl_rneg, 4 Wv, 5 Wr_pos+Wr_neg, 6 Wr_rpos+Wr_rneg
__global__ void k_prep(const float* __restrict__ Wl_pos, const float* __restrict__ Wl_neg,
                       const float* __restrict__ Wl_rpos, const float* __restrict__ Wl_rneg,
                       const float* __restrict__ Wv, const float* __restrict__ Wr_pos,
                       const float* __restrict__ Wr_neg, const float* __restrict__ Wr_rpos,
                       const float* __restrict__ Wr_rneg, ushort* __restrict__ wt){
  int tid = blockIdx.x * 256 + threadIdx.x;
  int n4 = tid & 31, k = (tid >> 5) & 127, l = (tid >> 12) & 7, m = tid >> 15;
  const float* s1; const float* s2 = nullptr;
  switch (m){
    case 0: s1 = Wl_pos;  break;
    case 1: s1 = Wl_neg;  break;
    case 2: s1 = Wl_rpos; break;
    case 3: s1 = Wl_rneg; break;
    case 4: s1 = Wv;      break;
    case 5: s1 = Wr_pos;  s2 = Wr_neg;  break;
    default: s1 = Wr_rpos; s2 = Wr_rneg; break;
  }
  size_t o = (size_t)l*16384 + (size_t)k*128 + n4*4;
  float4 w = *(const float4*)(s1 + o);
  if (s2){
    float4 w2 = *(const float4*)(s2 + o);
    w.x += w2.x; w.y += w2.y; w.z += w2.z; w.w += w2.w;
  }
  ushort* hi = wt + (size_t)((m*LL + l)*2    )*16384;
  ushort* lo = wt + (size_t)((m*LL + l)*2 + 1)*16384;
  float vv[4] = {w.x, w.y, w.z, w.w};
  #pragma unroll
  for (int e = 0; e < 4; ++e){
    int n = n4*4 + e;
    uint h = f2bf(vv[e]);
    float r = vv[e] - bf2f(h);
    hi[SW(n, k)] = (ushort)h;
    lo[SW(n, k)] = (ushort)f2bf(r);
  }
}

// ---------------- CSR build ----------------
__global__ void k_counti(const int* __restrict__ d, int* cnt, int n){
  int i = blockIdx.x * 256 + threadIdx.x;
  if (i < n) atomicAdd(&cnt[d[i]], 1);
}

#define SCAN256(ts, t) \
  for (int off = 1; off < 256; off <<= 1){ \
    int _a = (t >= off) ? ts[t - off] : 0; \
    __syncthreads(); \
    ts[t] += _a; \
    __syncthreads(); \
  }

// in-place safe (in==out)
__global__ void k_scanb(const int* __restrict__ in, int* __restrict__ out,
                        int* __restrict__ part, int n){
  __shared__ int ts[256];
  int b = blockIdx.x, t = threadIdx.x;
  int base = b*1024 + t*4;
  int v0 = (base+0 < n) ? in[base+0] : 0;
  int v1 = (base+1 < n) ? in[base+1] : 0;
  int v2 = (base+2 < n) ? in[base+2] : 0;
  int v3 = (base+3 < n) ? in[base+3] : 0;
  int s1 = v0, s2 = s1+v1, s3 = s2+v2, tsum = s3+v3;
  ts[t] = tsum; __syncthreads();
  SCAN256(ts, t)
  int excl = ts[t] - tsum;
  if (base+0 < n) out[base+0] = excl;
  if (base+1 < n) out[base+1] = excl + s1;
  if (base+2 < n) out[base+2] = excl + s2;
  if (base+3 < n) out[base+3] = excl + s3;
  if (t == 255) part[b] = ts[255];
}

__global__ void k_scanp(int* p, int nb){
  __shared__ int ts[256];
  __shared__ int carry;
  int t = threadIdx.x;
  if (t == 0) carry = 0;
  __syncthreads();
  for (int c = 0; c*256 < nb; ++c){
    int i = c*256 + t;
    int v = (i < nb) ? p[i] : 0;
    ts[t] = v; __syncthreads();
    SCAN256(ts, t)
    int excl = ts[t] - v + carry;
    if (i < nb) p[i] = excl;
    int tot = ts[255];
    __syncthreads();
    if (t == 0) carry += tot;
    __syncthreads();
  }
}

__global__ void k_scana(int* out, const int* __restrict__ part, int n){
  int i = blockIdx.x * 256 + threadIdx.x;
  if (i < n) out[i] += part[i >> 10];
}

// post-fill: ip[i] = end of segment i; start = i? ip[i-1] : 0
__global__ void k_fill(const int* __restrict__ dst, const int* __restrict__ pay,
                       int* cur, int* __restrict__ eo, int n){
  int i = blockIdx.x * 256 + threadIdx.x;
  if (i >= n) return;
  int p = atomicAdd(&cur[dst[i]], 1);
  eo[p] = pay[i];
}

// ---------------- v-side CSR gather-mean (wave per row, 8-deep index prefetch) ----------------
__global__ void k_vgather(const uint* __restrict__ ch,
                          const int* __restrict__ ipp, const int* __restrict__ epp,
                          const int* __restrict__ ipn, const int* __restrict__ epn,
                          uint* __restrict__ Up, uint* __restrict__ Un){
  int g = blockIdx.x * 256 + threadIdx.x;
  int v = g >> 6, lane = g & 63;
  if (v >= NVV) return;
  int sp = v ? ipp[v-1] : 0, ePos = ipp[v];
  int sn = v ? ipn[v-1] : 0, eNeg = ipn[v];
  int dp = ePos - sp, dn = eNeg - sn;
  // prefetch indices (contiguous CSR segment) -> independent row loads
  int a0 = dp>0 ? epp[sp+0] : 0, a1 = dp>1 ? epp[sp+1] : 0;
  int a2 = dp>2 ? epp[sp+2] : 0, a3 = dp>3 ? epp[sp+3] : 0;
  int a4 = dp>4 ? epp[sp+4] : 0, a5 = dp>5 ? epp[sp+5] : 0;
  int a6 = dp>6 ? epp[sp+6] : 0, a7 = dp>7 ? epp[sp+7] : 0;
  int b0 = dn>0 ? epn[sn+0] : 0, b1 = dn>1 ? epn[sn+1] : 0;
  int b2 = dn>2 ? epn[sn+2] : 0, b3 = dn>3 ? epn[sn+3] : 0;
  int b4 = dn>4 ? epn[sn+4] : 0, b5 = dn>5 ? epn[sn+5] : 0;
  int b6 = dn>6 ? epn[sn+6] : 0, b7 = dn>7 ? epn[sn+7] : 0;
  uint ua0 = dp>0 ? ch[(size_t)a0*64 + lane] : 0;
  uint ua1 = dp>1 ? ch[(size_t)a1*64 + lane] : 0;
  uint ua2 = dp>2 ? ch[(size_t)a2*64 + lane] : 0;
  uint ua3 = dp>3 ? ch[(size_t)a3*64 + lane] : 0;
  uint ua4 = dp>4 ? ch[(size_t)a4*64 + lane] : 0;
  uint ua5 = dp>5 ? ch[(size_t)a5*64 + lane] : 0;
  uint ua6 = dp>6 ? ch[(size_t)a6*64 + lane] : 0;
  uint ua7 = dp>7 ? ch[(size_t)a7*64 + lane] : 0;
  uint ub0 = dn>0 ? ch[(size_t)b0*64 + lane] : 0;
  uint ub1 = dn>1 ? ch[(size_t)b1*64 + lane] : 0;
  uint ub2 = dn>2 ? ch[(size_t)b2*64 + lane] : 0;
  uint ub3 = dn>3 ? ch[(size_t)b3*64 + lane] : 0;
  uint ub4 = dn>4 ? ch[(size_t)b4*64 + lane] : 0;
  uint ub5 = dn>5 ? ch[(size_t)b5*64 + lane] : 0;
  uint ub6 = dn>6 ? ch[(size_t)b6*64 + lane] : 0;
  uint ub7 = dn>7 ? ch[(size_t)b7*64 + lane] : 0;
  float p0, p1, n0, n1;
  p0  = bf2f(ua0 & 0xFFFFu); p1  = bf2f(ua0 >> 16);
  p0 += bf2f(ua1 & 0xFFFFu); p1 += bf2f(ua1 >> 16);
  p0 += bf2f(ua2 & 0xFFFFu); p1 += bf2f(ua2 >> 16);
  p0 += bf2f(ua3 & 0xFFFFu); p1 += bf2f(ua3 >> 16);
  p0 += bf2f(ua4 & 0xFFFFu); p1 += bf2f(ua4 >> 16);
  p0 += bf2f(ua5 & 0xFFFFu); p1 += bf2f(ua5 >> 16);
  p0 += bf2f(ua6 & 0xFFFFu); p1 += bf2f(ua6 >> 16);
  p0 += bf2f(ua7 & 0xFFFFu); p1 += bf2f(ua7 >> 16);
  n0  = bf2f(ub0 & 0xFFFFu); n1  = bf2f(ub0 >> 16);
  n0 += bf2f(ub1 & 0xFFFFu); n1 += bf2f(ub1 >> 16);
  n0 += bf2f(ub2 & 0xFFFFu); n1 += bf2f(ub2 >> 16);
  n0 += bf2f(ub3 & 0xFFFFu); n1 += bf2f(ub3 >> 16);
  n0 += bf2f(ub4 & 0xFFFFu); n1 += bf2f(ub4 >> 16);
  n0 += bf2f(ub5 & 0xFFFFu); n1 += bf2f(ub5 >> 16);
  n0 += bf2f(ub6 & 0xFFFFu); n1 += bf2f(ub6 >> 16);
  n0 += bf2f(ub7 & 0xFFFFu); n1 += bf2f(ub7 >> 16);
  for (int j = sp + 8; j < ePos; ++j){
    uint u = ch[(size_t)epp[j]*64 + lane];
    p0 += bf2f(u & 0xFFFFu); p1 += bf2f(u >> 16);
  }
  for (int j = sn + 8; j < eNeg; ++j){
    uint u = ch[(size_t)epn[j]*64 + lane];
    n0 += bf2f(u & 0xFFFFu); n1 += bf2f(u >> 16);
  }
  float ivp = 1.f / fmaxf((float)dp, 1.f);
  float ivn = 1.f / fmaxf((float)dn, 1.f);
  Up[(size_t)v*64 + lane] = pack2(p0*ivp, p1*ivp);
  Un[(size_t)v*64 + lane] = pack2(n0*ivn, n1*ivn);
}

// ---------------- MFMA GEMM building blocks (512 threads, 128x128 tile) ----------------
__device__ inline void stA_bf16(const uint4* __restrict__ A, ushort* As, int m0, int M, int t){
  #pragma unroll
  for (int j = 0; j < 4; ++j){
    int idx = j*512 + t, r = idx >> 4, c = idx & 15;
    uint4 v = make_uint4(0,0,0,0);
    if (m0 + r < M) v = A[(size_t)(m0 + r)*16 + c];
    *(uint4*)(As + SW(r, c*8)) = v;
  }
}

__device__ inline void stA_f32(const float* __restrict__ A, ushort* As, int m0, int M, int t){
  const float4* A4 = (const float4*)A;
  #pragma unroll
  for (int j = 0; j < 8; ++j){
    int idx = j*512 + t, r = idx >> 5, c = idx & 31;
    float4 v = make_float4(0.f,0.f,0.f,0.f);
    if (m0 + r < M) v = A4[(size_t)(m0 + r)*32 + c];
    uint2 u; u.x = pack2(v.x, v.y); u.y = pack2(v.z, v.w);
    *(uint2*)(As + SW(r, c*4)) = u;
  }
}

// register-staged A (bf16) and B tiles
__device__ inline void ldA_bf16(const uint4* __restrict__ A, uint4 ar[4], int m0, int M, int t){
  #pragma unroll
  for (int j = 0; j < 4; ++j){
    int idx = j*512 + t, r = idx >> 4, c = idx & 15;
    ar[j] = make_uint4(0,0,0,0);
    if (m0 + r < M) ar[j] = A[(size_t)(m0 + r)*16 + c];
  }
}
__device__ inline void wrA(const uint4 ar[4], ushort* As, int t){
  #pragma unroll
  for (int j = 0; j < 4; ++j){
    int idx = j*512 + t, r = idx >> 4, c = idx & 15;
    *(uint4*)(As + SW(r, c*8)) = ar[j];
  }
}
__device__ inline void ldB(const uint4* __restrict__ Bt, uint4 br[4], int t){
  #pragma unroll
  for (int j = 0; j < 4; ++j) br[j] = Bt[j*512 + t];
}
__device__ inline void wrB(ushort* Bs, const uint4 br[4], int t){
  #pragma unroll
  for (int j = 0; j < 4; ++j) ((uint4*)Bs)[j*512 + t] = br[j];
}

__device__ inline void stB(const uint4* __restrict__ Bt, ushort* Bs, int t){
  #pragma unroll
  for (int j = 0; j < 4; ++j) ((uint4*)Bs)[j*512 + t] = Bt[j*512 + t];
}

__device__ inline void kloop(const ushort* As, const ushort* Bs, int wr, int wc,
                             int l15, int g, f32x4 acc[2][4]){
  #pragma unroll
  for (int kk = 0; kk < 4; ++kk){
    int kb = kk*32 + g*8;
    bf16x8 a0 = *(const bf16x8*)(As + SW(wr*32 + l15,      kb));
    bf16x8 a1 = *(const bf16x8*)(As + SW(wr*32 + 16 + l15, kb));
    #pragma unroll
    for (int ni = 0; ni < 4; ++ni){
      int n = wc*64 + ni*16 + l15;
      bf16x8 b = *(const bf16x8*)(Bs + SW(n, kb));
      acc[0][ni] = MFMA16(a0, b, acc[0][ni]);
      acc[1][ni] = MFMA16(a1, b, acc[1][ni]);
    }
  }
}

__device__ inline void accStoreF(float* ldsF, f32x4 acc[2][4], int wr, int wc, int l15, int g){
  #pragma unroll
  for (int mi = 0; mi < 2; ++mi)
    #pragma unroll
    for (int ni = 0; ni < 4; ++ni)
      #pragma unroll
      for (int j = 0; j < 4; ++j)
        ldsF[(wr*32 + mi*16 + g*4 + j)*128 + wc*64 + ni*16 + l15] = acc[mi][ni][j];
}

// f32 tile store, float4-group XOR swizzled (for row-wise readers)
__device__ inline void accStoreFsw(float* ldsF, f32x4 acc[2][4], int wr, int wc, int l15, int g){
  #pragma unroll
  for (int mi = 0; mi < 2; ++mi)
    #pragma unroll
    for (int ni = 0; ni < 4; ++ni)
      #pragma unroll
      for (int j = 0; j < 4; ++j){
        int r = wr*32 + mi*16 + g*4 + j;
        int c = wc*64 + ni*16 + l15;
        ldsF[r*128 + (((c >> 2) ^ (r & 31)) << 2) + (c & 3)] = acc[mi][ni][j];
      }
}

__device__ inline void accStoreBf(ushort* dst, f32x4 acc[2][4], int wr, int wc, int l15, int g){
  #pragma unroll
  for (int mi = 0; mi < 2; ++mi)
    #pragma unroll
    for (int ni = 0; ni < 4; ++ni)
      #pragma unroll
      for (int j = 0; j < 4; ++j)
        dst[(wr*32 + mi*16 + g*4 + j)*128 + wc*64 + ni*16 + l15] =
            (ushort)f2bf(acc[mi][ni][j]);
}

#define MMHEAD \
  __shared__ ushort lds[32768]; \
  ushort* As = lds; ushort* Bs = lds + 16384; \
  float* accumF = (float*)lds; \
  int t = threadIdx.x, m0 = blockIdx.x * 128; \
  int w = t >> 6, l = t & 63, wr = w >> 1, wc = w & 1, l15 = l & 15, g = l >> 4; \
  const f32x4 zz = {0.f, 0.f, 0.f, 0.f}; \
  (void)accumF;

#define ZACC(A) { \
  _Pragma("unroll") for (int mi_ = 0; mi_ < 2; ++mi_) \
    _Pragma("unroll") for (int ni_ = 0; ni_ < 4; ++ni_) A[mi_][ni_] = zz; }

// ---- fused v-side per layer (B stages register-prefetched):
//  Yp = v_h@Wl_pos, Yn = v_h@Wl_neg   (written to global for k_mm_c)
//  vmid = 0.9*(aggp@Wl_rpos + aggn@Wl_rneg + v_h@wsum_v + blp + bln) + 0.1*relu(vemb)
//  v_h  = relu(omb*vmid + beta*(vmid@Wv + bv) + v_h)     (in-place)
__global__ __launch_bounds__(512) void k_fused_v(
    const uint4* __restrict__ AggP, const uint4* __restrict__ AggN,
    const uint4* __restrict__ Bph, const uint4* __restrict__ Bpl,   // Wl_rpos
    const uint4* __restrict__ Bnh, const uint4* __restrict__ Bnl,   // Wl_rneg
    const uint4* __restrict__ Bfh, const uint4* __restrict__ Bfl,   // wsum_v
    const uint4* __restrict__ Byph, const uint4* __restrict__ Bypl, // Wl_pos
    const uint4* __restrict__ Bynh, const uint4* __restrict__ Bynl, // Wl_neg
    const uint4* __restrict__ Bvh, const uint4* __restrict__ Bvl,   // Wv
    const float* __restrict__ xv, const float* __restrict__ Wve, const float* __restrict__ bve,
    const float* __restrict__ blp, const float* __restrict__ bln, const float* __restrict__ bvv,
    float omb, float beta,
    uint4* __restrict__ Yp, uint4* __restrict__ Yn, float* vh, int M){
  MMHEAD
  f32x4 accM[2][4], accP[2][4], accN[2][4];
  ZACC(accM) ZACC(accP) ZACC(accN)
  uint4 br[4], ar[4];

  // stage 1: A=AggP, B=Wl_rpos hi
  ldB(Bph, br, t);
  stA_bf16(AggP, As, m0, M, t);
  wrB(Bs, br, t);
  __syncthreads();
  ldB(Bpl, br, t);
  kloop(As, Bs, wr, wc, l15, g, accM); __syncthreads();
  // stage 2: Wl_rpos lo
  wrB(Bs, br, t); __syncthreads();
  ldB(Bnh, br, t); ldA_bf16(AggN, ar, m0, M, t);
  kloop(As, Bs, wr, wc, l15, g, accM); __syncthreads();
  // stage 3: A=AggN, Wl_rneg hi
  wrB(Bs, br, t); wrA(ar, As, t); __syncthreads();
  ldB(Bnl, br, t);
  kloop(As, Bs, wr, wc, l15, g, accM); __syncthreads();
  // stage 4: Wl_rneg lo
  wrB(Bs, br, t); __syncthreads();
  ldB(Bfh, br, t);
  kloop(As, Bs, wr, wc, l15, g, accM); __syncthreads();
  // stage 5: A=v_h (f32), wsum_v hi
  wrB(Bs, br, t); stA_f32(vh, As, m0, M, t); __syncthreads();
  ldB(Bfl, br, t);
  kloop(As, Bs, wr, wc, l15, g, accM); __syncthreads();
  // stage 6: wsum_v lo
  wrB(Bs, br, t); __syncthreads();
  ldB(Byph, br, t);
  kloop(As, Bs, wr, wc, l15, g, accM); __syncthreads();
  // stage 7: Wl_pos hi
  wrB(Bs, br, t); __syncthreads();
  ldB(Bypl, br, t);
  kloop(As, Bs, wr, wc, l15, g, accP); __syncthreads();
  // stage 8: Wl_pos lo
  wrB(Bs, br, t); __syncthreads();
  ldB(Bynh, br, t);
  kloop(As, Bs, wr, wc, l15, g, accP); __syncthreads();
  // stage 9: Wl_neg hi
  wrB(Bs, br, t); __syncthreads();
  ldB(Bynl, br, t);
  kloop(As, Bs, wr, wc, l15, g, accN); __syncthreads();
  // stage 10: Wl_neg lo (prefetch Wv hi — overlaps whole epilogue)
  wrB(Bs, br, t); __syncthreads();
  ldB(Bvh, br, t);
  kloop(As, Bs, wr, wc, l15, g, accN);

  // write Yp/Yn through LDS repack
  __syncthreads();
  accStoreBf(lds,         accP, wr, wc, l15, g);
  accStoreBf(lds + 16384, accN, wr, wc, l15, g);
  __syncthreads();
  #pragma unroll
  for (int j = 0; j < 4; ++j){
    int idx = j*512 + t, r = idx >> 4, c = idx & 15;
    if (m0 + r < M){
      Yp[(size_t)(m0 + r)*16 + c] = ((const uint4*)lds)[idx];
      Yn[(size_t)(m0 + r)*16 + c] = ((const uint4*)(lds + 16384))[idx];
    }
  }
  __syncthreads();

  // vmid epilogue: accM -> full f32 tile -> (regs) -> bf16 swizzled As
  accStoreF(accumF, accM, wr, wc, l15, g);
  __syncthreads();
  float4 vreg[8];
  #pragma unroll
  for (int j = 0; j < 8; ++j){
    int idx = j*512 + t, r = idx >> 5, c4 = idx & 31;
    int row = m0 + r;
    float4 o = make_float4(0.f,0.f,0.f,0.f);
    if (row < M){
      float4 a4 = ((const float4*)accumF)[r*32 + c4];
      float4 bp = ((const float4*)blp)[c4];
      float4 bn = ((const float4*)bln)[c4];
      float4 h = relu4(vemb4(xv, Wve, bve, row, c4*4));
      o.x = 0.9f*(a4.x + bp.x + bn.x) + 0.1f*h.x;
      o.y = 0.9f*(a4.y + bp.y + bn.y) + 0.1f*h.y;
      o.z = 0.9f*(a4.z + bp.z + bn.z) + 0.1f*h.z;
      o.w = 0.9f*(a4.w + bp.w + bn.w) + 0.1f*h.w;
    }
    vreg[j] = o;
  }
  __syncthreads();
  #pragma unroll
  for (int j = 0; j < 8; ++j){
    int idx = j*512 + t, r = idx >> 5, c4 = idx & 31;
    uint2 u; u.x = pack2(vreg[j].x, vreg[j].y); u.y = pack2(vreg[j].z, vreg[j].w);
    *(uint2*)(As + SW(r, c4*4)) = u;
  }
  // stage 11: vmid @ Wv hi (Bvh already in br)
  wrB(Bs, br, t);
  __syncthreads();
  ldB(Bvl, br, t);
  f32x4 accT[2][4];
  ZACC(accT)
  kloop(As, Bs, wr, wc, l15, g, accT); __syncthreads();
  // stage 12: Wv lo
  wrB(Bs, br, t); __syncthreads();
  kloop(As, Bs, wr, wc, l15, g, accT);

  // final v_h update via 32KB half-tiles in Bs (coalesced float4 RMW on vh)
  float* ldsH = (float*)Bs;
  #pragma unroll
  for (int half = 0; half < 2; ++half){
    __syncthreads();   // protect Bs (kloop reads / previous epilogue reads)
    if ((wr >> 1) == half){
      int rbase = (wr & 1)*32;
      #pragma unroll
      for (int mi = 0; mi < 2; ++mi)
        #pragma unroll
        for (int ni = 0; ni < 4; ++ni)
          #pragma unroll
          for (int j = 0; j < 4; ++j)
            ldsH[(rbase + mi*16 + g*4 + j)*128 + wc*64 + ni*16 + l15] = accT[mi][ni][j];
    }
    __syncthreads();
    #pragma unroll
    for (int j = 0; j < 4; ++j){
      int idx = j*512 + t, r2 = idx >> 5, c4 = idx & 31;
      int row = m0 + half*64 + r2;
      if (row >= M) continue;
      float4 a4 = ((const float4*)ldsH)[r2*32 + c4];
      uint2 um = *(const uint2*)(As + SW(half*64 + r2, c4*4));
      float4 bb = ((const float4*)bvv)[c4];
      float4 vo = *(const float4*)(vh + (size_t)row*HH + c4*4);
      float m0f = bf2f(um.x & 0xFFFFu), m1f = bf2f(um.x >> 16);
      float m2f = bf2f(um.y & 0xFFFFu), m3f = bf2f(um.y >> 16);
      float4 o;
      o.x = fmaxf(omb*m0f + beta*(a4.x + bb.x) + vo.x, 0.f);
      o.y = fmaxf(omb*m1f + beta*(a4.y + bb.y) + vo.y, 0.f);
      o.z = fmaxf(omb*m2f + beta*(a4.z + bb.z) + vo.z, 0.f);
      o.w = fmaxf(omb*m3f + beta*(a4.w + bb.w) + vo.w, 0.f);
      *(float4*)(vh + (size_t)row*HH + c4*4) = o;
    }
  }
}

// ---- clause update (in-place c_h), 16-lanes-per-row gather with 4-deep prefetch:
// c_h = relu(0.9*(mean_p(Yp) + mean_n(Yn) + c_h@wsum_c + blp + bln) + 0.1*relu(cemb)) ----
__device__ inline void addrow8(float f[8], uint4 u){
  f[0] += bf2f(u.x & 0xFFFFu); f[1] += bf2f(u.x >> 16);
  f[2] += bf2f(u.y & 0xFFFFu); f[3] += bf2f(u.y >> 16);
  f[4] += bf2f(u.z & 0xFFFFu); f[5] += bf2f(u.z >> 16);
  f[6] += bf2f(u.w & 0xFFFFu); f[7] += bf2f(u.w >> 16);
}

__global__ __launch_bounds__(512) void k_mm_c(const uint4* ch,
    const uint4* __restrict__ Bh, const uint4* __restrict__ Bl,
    const int* __restrict__ ipp, const int* __restrict__ ecp,
    const int* __restrict__ ipn, const int* __restrict__ ecn,
    const uint4* __restrict__ Yp, const uint4* __restrict__ Yn,
    const float* __restrict__ xc, const float* __restrict__ Wc, const float* __restrict__ bc,
    const float* __restrict__ blp, const float* __restrict__ bln,
    uint4* chout){
  MMHEAD
  f32x4 acc[2][4];
  ZACC(acc)
  stA_bf16(ch, As, m0, NCC, t); stB(Bh, Bs, t); __syncthreads();
  kloop(As, Bs, wr, wc, l15, g, acc); __syncthreads();
  stB(Bl, Bs, t); __syncthreads();
  kloop(As, Bs, wr, wc, l15, g, acc); __syncthreads();
  accStoreFsw(accumF, acc, wr, wc, l15, g);
  __syncthreads();

  // phase 3: 16 lanes per row, 4-deep dual-polarity prefetch
  int c16 = t & 15;
  int rg  = t >> 4;            // 0..31
  const uint4 z4 = make_uint4(0,0,0,0);
  #pragma unroll
  for (int pass = 0; pass < 4; ++pass){
    int r = pass*32 + rg;
    int row = m0 + r;
    if (row >= NCC) continue;
    int sp = row ? ipp[row-1] : 0, ePos = ipp[row];
    int sn = row ? ipn[row-1] : 0, eNeg = ipn[row];
    int dp = ePos - sp, dn = eNeg - sn;
    int ia0 = dp>0 ? ecp[sp+0] : 0, ia1 = dp>1 ? ecp[sp+1] : 0;
    int ia2 = dp>2 ? ecp[sp+2] : 0, ia3 = dp>3 ? ecp[sp+3] : 0;
    int ib0 = dn>0 ? ecn[sn+0] : 0, ib1 = dn>1 ? ecn[sn+1] : 0;
    int ib2 = dn>2 ? ecn[sn+2] : 0, ib3 = dn>3 ? ecn[sn+3] : 0;
    uint4 ra0 = dp>0 ? Yp[(size_t)ia0*16 + c16] : z4;
    uint4 ra1 = dp>1 ? Yp[(size_t)ia1*16 + c16] : z4;
    uint4 ra2 = dp>2 ? Yp[(size_t)ia2*16 + c16] : z4;
    uint4 ra3 = dp>3 ? Yp[(size_t)ia3*16 + c16] : z4;
    uint4 rb0 = dn>0 ? Yn[(size_t)ib0*16 + c16] : z4;
    uint4 rb1 = dn>1 ? Yn[(size_t)ib1*16 + c16] : z4;
    uint4 rb2 = dn>2 ? Yn[(size_t)ib2*16 + c16] : z4;
    uint4 rb3 = dn>3 ? Yn[(size_t)ib3*16 + c16] : z4;
    float fp[8] = {0,0,0,0,0,0,0,0};
    float fn[8] = {0,0,0,0,0,0,0,0};
    addrow8(fp, ra0); addrow8(fp, ra1); addrow8(fp, ra2); addrow8(fp, ra3);
    addrow8(fn, rb0); addrow8(fn, rb1); addrow8(fn, rb2); addrow8(fn, rb3);
    for (int j = sp + 4; j < ePos; ++j) addrow8(fp, Yp[(size_t)ecp[j]*16 + c16]);
    for (int j = sn + 4; j < eNeg; ++j) addrow8(fn, Yn[(size_t)ecn[j]*16 + c16]);
    float invp = 1.f / fmaxf((float)dp, 1.f);
    float invn = 1.f / fmaxf((float)dn, 1.f);

    int gi0 = c16*2, gi1 = gi0 + 1;
    float4 res0 = ((const float4*)accumF)[r*32 + (gi0 ^ (r & 31))];
    float4 res1 = ((const float4*)accumF)[r*32 + (gi1 ^ (r & 31))];
    float4 wc0 = ((const float4*)Wc)[gi0],  wc1 = ((const float4*)Wc)[gi1];
    float4 bc0 = ((const float4*)bc)[gi0],  bc1 = ((const float4*)bc)[gi1];
    float4 bp0 = ((const float4*)blp)[gi0], bp1 = ((const float4*)blp)[gi1];
    float4 bn0 = ((const float4*)bln)[gi0], bn1 = ((const float4*)bln)[gi1];
    float xcv = xc[row];
    float res[8] = {res0.x,res0.y,res0.z,res0.w, res1.x,res1.y,res1.z,res1.w};
    float wcv[8] = {wc0.x,wc0.y,wc0.z,wc0.w, wc1.x,wc1.y,wc1.z,wc1.w};
    float bcv[8] = {bc0.x,bc0.y,bc0.z,bc0.w, bc1.x,bc1.y,bc1.z,bc1.w};
    float bpv[8] = {bp0.x,bp0.y,bp0.z,bp0.w, bp1.x,bp1.y,bp1.z,bp1.w};
    float bnv[8] = {bn0.x,bn0.y,bn0.z,bn0.w, bn1.x,bn1.y,bn1.z,bn1.w};
    float o[8];
    #pragma unroll
    for (int k = 0; k < 8; ++k){
      float h = fmaxf(fmaf(xcv, wcv[k], bcv[k]), 0.f);
      float m = fmaf(fp[k], invp, fn[k]*invn);
      o[k] = fmaxf(0.9f*(m + res[k] + bpv[k] + bnv[k]) + 0.1f*h, 0.f);
    }
    uint4 u;
    u.x = pack2(o[0], o[1]); u.y = pack2(o[2], o[3]);
    u.z = pack2(o[4], o[5]); u.w = pack2(o[6], o[7]);
    chout[(size_t)row*16 + c16] = u;
  }
}

// out[i] = dot(v_h[i,:], W_fin) + b_fin   (one wave per row)
__global__ void k_final(const float* __restrict__ vh, const float* __restrict__ wf,
                        const float* __restrict__ bf, float* __restrict__ out){
  int wid = (blockIdx.x * 256 + threadIdx.x) >> 6;
  if (wid >= NVV) return;
  int lane = threadIdx.x & 63;
  float2 a = *(const float2*)(vh + (size_t)wid*HH + lane*2);
  float2 w = *(const float2*)(wf + lane*2);
  float s = a.x*w.x + a.y*w.y;
  #pragma unroll
  for (int off = 32; off > 0; off >>= 1) s += __shfl_down(s, off);
  if (lane == 0) out[wid] = s + bf[0];
}

// ---------------- orchestration ----------------
extern "C" void kernel_launch(void* const* d_in, const int* in_sizes, int n_in,
                              void* d_out, int out_size, void* d_ws, size_t ws_size,
                              hipStream_t stream) {
  const float* xv  = (const float*)d_in[0];
  const float* xc  = (const float*)d_in[1];
  const int*   ep  = (const int*)d_in[2];
  const int*   en  = (const int*)d_in[3];
  const float* Wve = (const float*)d_in[4];
  const float* bve = (const float*)d_in[5];
  const float* Wce = (const float*)d_in[6];
  const float* bce = (const float*)d_in[7];
  const float* Wl_pos  = (const float*)d_in[8];
  const float* bl_pos  = (const float*)d_in[9];
  const float* Wr_pos  = (const float*)d_in[10];
  const float* Wl_neg  = (const float*)d_in[11];
  const float* bl_neg  = (const float*)d_in[12];
  const float* Wr_neg  = (const float*)d_in[13];
  const float* Wl_rpos = (const float*)d_in[14];
  const float* bl_rpos = (const float*)d_in[15];
  const float* Wr_rpos = (const float*)d_in[16];
  const float* Wl_rneg = (const float*)d_in[17];
  const float* bl_rneg = (const float*)d_in[18];
  const float* Wr_rneg = (const float*)d_in[19];
  const float* Wv  = (const float*)d_in[20];
  const float* bv  = (const float*)d_in[21];
  const float* Wf  = (const float*)d_in[22];
  const float* bf  = (const float*)d_in[23];
  float* out = (float*)d_out;

  size_t off = 0;
  auto alloc = [&](size_t bytes) -> void* {
    void* p = (char*)d_ws + off;
    off = (off + bytes + 255) & ~(size_t)255;
    return p;
  };
  uint*   c_h  = (uint*)  alloc((size_t)NCC*64*sizeof(uint));   // bf16 NCxH
  float*  v_h  = (float*) alloc((size_t)NVV*HH*sizeof(float));  // f32  NVxH
  uint*   U1   = (uint*)  alloc((size_t)NVV*64*sizeof(uint));   // bf16 NVxH (agg_p -> Yp)
  uint*   U2   = (uint*)  alloc((size_t)NVV*64*sizeof(uint));   // bf16 NVxH (agg_n -> Yn)
  ushort* wt   = (ushort*)alloc((size_t)7*LL*2*16384*sizeof(ushort));
  int*   ipc_p = (int*)  alloc((size_t)NCC*sizeof(int));
  int*   ec_p  = (int*)  alloc((size_t)EE*sizeof(int));
  int*   ipc_n = (int*)  alloc((size_t)NCC*sizeof(int));
  int*   ec_n  = (int*)  alloc((size_t)EE*sizeof(int));
  int*   ipv_p = (int*)  alloc((size_t)NVV*sizeof(int));
  int*   ev_p  = (int*)  alloc((size_t)EE*sizeof(int));
  int*   ipv_n = (int*)  alloc((size_t)NVV*sizeof(int));
  int*   ev_n  = (int*)  alloc((size_t)EE*sizeof(int));
  int*   part  = (int*)  alloc(4096);
  if (off > ws_size){
    k_sentinel<<<1, 64, 0, stream>>>(out, (float)(ws_size >> 20));
    return;
  }

  const int TB = 256;
  const int gE  = (EE + TB-1)/TB;
  const int gV  = (NVV*32 + TB-1)/TB;
  const int gC  = (NCC*32 + TB-1)/TB;
  const int gGv = (NVV + 127)/128;   // 782
  const int gGc = (NCC + 127)/128;   // 3282
  const int gWd = (NVV*64 + TB-1)/TB;

  auto wp = [&](int m, int l, int h) -> const uint4* {
    return (const uint4*)(wt + (size_t)((m*LL + l)*2 + h)*16384);
  };

  auto build = [&](const int* dst, const int* pay, int nd, int* ip, int* eo){
    hipMemsetAsync(ip, 0, (size_t)nd*sizeof(int), stream);
    k_counti<<<gE, TB, 0, stream>>>(dst, ip, EE);
    int nb = (nd + 1023)/1024;
    k_scanb<<<nb, TB, 0, stream>>>(ip, ip, part, nd);
    k_scanp<<<1, TB, 0, stream>>>(part, nb);
    k_scana<<<(nd + TB-1)/TB, TB, 0, stream>>>(ip, part, nd);
    k_fill<<<gE, TB, 0, stream>>>(dst, pay, ip, eo, EE);
  };
  build(ep + EE, ep,      NCC, ipc_p, ec_p);
  build(en + EE, en,      NCC, ipc_n, ec_n);
  build(ep,      ep + EE, NVV, ipv_p, ev_p);
  build(en,      en + EE, NVV, ipv_n, ev_n);

  k_prep<<<(7*LL*128*32)/TB, TB, 0, stream>>>(Wl_pos, Wl_neg, Wl_rpos, Wl_rneg, Wv,
                                              Wr_pos, Wr_neg, Wr_rpos, Wr_rneg, wt);

  k_embed_v<<<gV, TB, 0, stream>>>(xv, Wve, bve, v_h);
  k_embed_c<<<gC, TB, 0, stream>>>(xc, Wce, bce, c_h);

  for (int l = 0; l < LL; ++l){
    const size_t bo = (size_t)l*HH;
    double beta_d = log(0.5/(double)(l+1) + 1.0);

    // agg_p/agg_n from OLD c_h
    k_vgather<<<gWd, TB, 0, stream>>>(c_h, ipv_p, ev_p, ipv_n, ev_n, U1, U2);
    // fused v-side: vmid + Y + v_h update (U1/U2: agg in, Y out)
    k_fused_v<<<gGv, 512, 0, stream>>>((const uint4*)U1, (const uint4*)U2,
                                       wp(2,l,0), wp(2,l,1), wp(3,l,0), wp(3,l,1),
                                       wp(6,l,0), wp(6,l,1),
                                       wp(0,l,0), wp(0,l,1), wp(1,l,0), wp(1,l,1),
                                       wp(4,l,0), wp(4,l,1),
                                       xv, Wve, bve, bl_rpos + bo, bl_rneg + bo, bv + bo,
                                       (float)(1.0 - beta_d), (float)beta_d,
                                       (uint4*)U1, (uint4*)U2, v_h, NVV);
    // clause update, in-place c_h
    k_mm_c<<<gGc, 512, 0, stream>>>((const uint4*)c_h, wp(5,l,0), wp(5,l,1),
                                    ipc_p, ec_p, ipc_n, ec_n,
                                    (const uint4*)U1, (const uint4*)U2,
                                    xc, Wce, bce, bl_pos + bo, bl_neg + bo,
                                    (uint4*)c_h);
  }

  k_final<<<gWd, TB, 0, stream>>>(v_h, Wf, bf, out);
}

// Round 9
// 3456.261 us; speedup vs baseline: 1.1581x; 1.1581x over previous
//
#include <hip/hip_runtime.h>
#include <math.h>

#define NVV 100000
#define NCC 420000
#define EE  630000
#define HH  128
#define LL  8

typedef unsigned int uint;
typedef unsigned short ushort;
typedef __attribute__((ext_vector_type(8))) short bf16x8;
typedef __attribute__((ext_vector_type(4))) float f32x4;

#define MFMA16(a,b,c) __builtin_amdgcn_mfma_f32_16x16x32_bf16(a,b,c,0,0,0)
// swizzled ushort index within a [128 rows][128 cols-of-bf16] LDS tile
#define SW(r,k) (((r)<<7) + ((k) ^ (((r)&7)<<3)))

// ---------------- bf16 helpers (bit-level, RNE) ----------------
__device__ inline float bf2f(uint u){ return __uint_as_float(u << 16); }
__device__ inline uint  f2bf(float f){
  uint b = __float_as_uint(f);
  return (b + 0x7FFFu + ((b >> 16) & 1u)) >> 16;
}
__device__ inline uint pack2(float a, float b){ return f2bf(a) | (f2bf(b) << 16); }
__device__ inline float4 relu4(float4 v){
  v.x = fmaxf(v.x, 0.f); v.y = fmaxf(v.y, 0.f);
  v.z = fmaxf(v.z, 0.f); v.w = fmaxf(v.w, 0.f);
  return v;
}

__global__ void k_sentinel(float* out, float v){
  if (blockIdx.x == 0 && threadIdx.x == 0) out[0] = v;
}

// ---------------- embeddings ----------------
__device__ inline float4 vemb4(const float* __restrict__ xv, const float* __restrict__ W,
                               const float* __restrict__ b, int i, int h4){
  float x0 = xv[4*i+0], x1 = xv[4*i+1], x2 = xv[4*i+2], x3 = xv[4*i+3];
  float4 w0 = *(const float4*)(W + 0*HH + h4);
  float4 w1 = *(const float4*)(W + 1*HH + h4);
  float4 w2 = *(const float4*)(W + 2*HH + h4);
  float4 w3 = *(const float4*)(W + 3*HH + h4);
  float4 bb = *(const float4*)(b + h4);
  float4 r;
  r.x = fmaf(x0,w0.x, fmaf(x1,w1.x, fmaf(x2,w2.x, fmaf(x3,w3.x, bb.x))));
  r.y = fmaf(x0,w0.y, fmaf(x1,w1.y, fmaf(x2,w2.y, fmaf(x3,w3.y, bb.y))));
  r.z = fmaf(x0,w0.z, fmaf(x1,w1.z, fmaf(x2,w2.z, fmaf(x3,w3.z, bb.z))));
  r.w = fmaf(x0,w0.w, fmaf(x1,w1.w, fmaf(x2,w2.w, fmaf(x3,w3.w, bb.w))));
  return r;
}

__global__ void k_embed_v(const float* __restrict__ xv, const float* __restrict__ W,
                          const float* __restrict__ b, float* __restrict__ out){
  int tid = blockIdx.x * 256 + threadIdx.x;
  int i = tid >> 5;
  if (i >= NVV) return;
  int h4 = (tid & 31) << 2;
  *(float4*)(out + (size_t)i*HH + h4) = relu4(vemb4(xv, W, b, i, h4));
}

__global__ void k_embed_c(const float* __restrict__ xc, const float* __restrict__ W,
                          const float* __restrict__ b, uint* __restrict__ out){
  int tid = blockIdx.x * 256 + threadIdx.x;
  int i = tid >> 5;
  if (i >= NCC) return;
  int c2 = tid & 31;
  int h4 = c2 << 2;
  float x0 = xc[i];
  float4 w = *(const float4*)(W + h4);
  float4 bb = *(const float4*)(b + h4);
  float4 r;
  r.x = fmaxf(fmaf(x0, w.x, bb.x), 0.f);
  r.y = fmaxf(fmaf(x0, w.y, bb.y), 0.f);
  r.z = fmaxf(fmaf(x0, w.z, bb.z), 0.f);
  r.w = fmaxf(fmaf(x0, w.w, bb.w), 0.f);
  uint2 o; o.x = pack2(r.x, r.y); o.y = pack2(r.z, r.w);
  *(uint2*)(out + (size_t)i*64 + c2*2) = o;
}

// ---------------- weight prep: transpose + swizzle + hi/lo split ----------------
// wt layout: [mat 0..6][layer 0..7][hi/lo][16384 ushorts], element (n,k) at SW(n,k)
// mats: 0 Wl_pos, 1 Wl_neg, 2 Wl_rpos, 3 Wl_rneg, 4 Wv, 5 Wr_pos+Wr_neg, 6 Wr_rpos+Wr_rneg
__global__ void k_prep(const float* __restrict__ Wl_pos, const float* __restrict__ Wl_neg,
                       const float* __restrict__ Wl_rpos, const float* __restrict__ Wl_rneg,
                       const float* __restrict__ Wv, const float* __restrict__ Wr_pos,
                       const float* __restrict__ Wr_neg, const float* __restrict__ Wr_rpos,
                       const float* __restrict__ Wr_rneg, ushort* __restrict__ wt){
  int tid = blockIdx.x * 256 + threadIdx.x;
  int n4 = tid & 31, k = (tid >> 5) & 127, l = (tid >> 12) & 7, m = tid >> 15;
  const float* s1; const float* s2 = nullptr;
  switch (m){
    case 0: s1 = Wl_pos;  break;
    case 1: s1 = Wl_neg;  break;
    case 2: s1 = Wl_rpos; break;
    case 3: s1 = Wl_rneg; break;
    case 4: s1 = Wv;      break;
    case 5: s1 = Wr_pos;  s2 = Wr_neg;  break;
    default: s1 = Wr_rpos; s2 = Wr_rneg; break;
  }
  size_t o = (size_t)l*16384 + (size_t)k*128 + n4*4;
  float4 w = *(const float4*)(s1 + o);
  if (s2){
    float4 w2 = *(const float4*)(s2 + o);
    w.x += w2.x; w.y += w2.y; w.z += w2.z; w.w += w2.w;
  }
  ushort* hi = wt + (size_t)((m*LL + l)*2    )*16384;
  ushort* lo = wt + (size_t)((m*LL + l)*2 + 1)*16384;
  float vv[4] = {w.x, w.y, w.z, w.w};
  #pragma unroll
  for (int e = 0; e < 4; ++e){
    int n = n4*4 + e;
    uint h = f2bf(vv[e]);
    float r = vv[e] - bf2f(h);
    hi[SW(n, k)] = (ushort)h;
    lo[SW(n, k)] = (ushort)f2bf(r);
  }
}

// ---------------- CSR build ----------------
__global__ void k_counti(const int* __restrict__ d, int* cnt, int n){
  int i = blockIdx.x * 256 + threadIdx.x;
  if (i < n) atomicAdd(&cnt[d[i]], 1);
}

#define SCAN256(ts, t) \
  for (int off = 1; off < 256; off <<= 1){ \
    int _a = (t >= off) ? ts[t - off] : 0; \
    __syncthreads(); \
    ts[t] += _a; \
    __syncthreads(); \
  }

// in-place safe (in==out)
__global__ void k_scanb(const int* __restrict__ in, int* __restrict__ out,
                        int* __restrict__ part, int n){
  __shared__ int ts[256];
  int b = blockIdx.x, t = threadIdx.x;
  int base = b*1024 + t*4;
  int v0 = (base+0 < n) ? in[base+0] : 0;
  int v1 = (base+1 < n) ? in[base+1] : 0;
  int v2 = (base+2 < n) ? in[base+2] : 0;
  int v3 = (base+3 < n) ? in[base+3] : 0;
  int s1 = v0, s2 = s1+v1, s3 = s2+v2, tsum = s3+v3;
  ts[t] = tsum; __syncthreads();
  SCAN256(ts, t)
  int excl = ts[t] - tsum;
  if (base+0 < n) out[base+0] = excl;
  if (base+1 < n) out[base+1] = excl + s1;
  if (base+2 < n) out[base+2] = excl + s2;
  if (base+3 < n) out[base+3] = excl + s3;
  if (t == 255) part[b] = ts[255];
}

__global__ void k_scanp(int* p, int nb){
  __shared__ int ts[256];
  __shared__ int carry;
  int t = threadIdx.x;
  if (t == 0) carry = 0;
  __syncthreads();
  for (int c = 0; c*256 < nb; ++c){
    int i = c*256 + t;
    int v = (i < nb) ? p[i] : 0;
    ts[t] = v; __syncthreads();
    SCAN256(ts, t)
    int excl = ts[t] - v + carry;
    if (i < nb) p[i] = excl;
    int tot = ts[255];
    __syncthreads();
    if (t == 0) carry += tot;
    __syncthreads();
  }
}

__global__ void k_scana(int* out, const int* __restrict__ part, int n){
  int i = blockIdx.x * 256 + threadIdx.x;
  if (i < n) out[i] += part[i >> 10];
}

// post-fill: ip[i] = end of segment i; start = i? ip[i-1] : 0
__global__ void k_fill(const int* __restrict__ dst, const int* __restrict__ pay,
                       int* cur, int* __restrict__ eo, int n){
  int i = blockIdx.x * 256 + threadIdx.x;
  if (i >= n) return;
  int p = atomicAdd(&cur[dst[i]], 1);
  eo[p] = pay[i];
}

// ---------------- v-side CSR gather-mean (wave per row, polarity-interleaved) ----------------
__global__ void k_vgather(const uint* __restrict__ ch,
                          const int* __restrict__ ipp, const int* __restrict__ epp,
                          const int* __restrict__ ipn, const int* __restrict__ epn,
                          uint* __restrict__ Up, uint* __restrict__ Un){
  int g = blockIdx.x * 256 + threadIdx.x;
  int v = g >> 6, lane = g & 63;
  if (v >= NVV) return;
  int sp = v ? ipp[v-1] : 0, ePos = ipp[v];
  int sn = v ? ipn[v-1] : 0, eNeg = ipn[v];
  float p0 = 0.f, p1 = 0.f, n0 = 0.f, n1 = 0.f;
  int jp = sp, jn = sn;
  while (jp < ePos && jn < eNeg){
    uint up = ch[(size_t)epp[jp]*64 + lane];
    uint un = ch[(size_t)epn[jn]*64 + lane];
    p0 += bf2f(up & 0xFFFFu); p1 += bf2f(up >> 16);
    n0 += bf2f(un & 0xFFFFu); n1 += bf2f(un >> 16);
    ++jp; ++jn;
  }
  for (; jp < ePos; ++jp){
    uint up = ch[(size_t)epp[jp]*64 + lane];
    p0 += bf2f(up & 0xFFFFu); p1 += bf2f(up >> 16);
  }
  for (; jn < eNeg; ++jn){
    uint un = ch[(size_t)epn[jn]*64 + lane];
    n0 += bf2f(un & 0xFFFFu); n1 += bf2f(un >> 16);
  }
  float ivp = 1.f / fmaxf((float)(ePos - sp), 1.f);
  float ivn = 1.f / fmaxf((float)(eNeg - sn), 1.f);
  Up[(size_t)v*64 + lane] = pack2(p0*ivp, p1*ivp);
  Un[(size_t)v*64 + lane] = pack2(n0*ivn, n1*ivn);
}

// ---------------- MFMA GEMM building blocks (512 threads, 128x128 tile) ----------------
__device__ inline void stA_bf16(const uint4* __restrict__ A, ushort* As, int m0, int M, int t){
  #pragma unroll
  for (int j = 0; j < 4; ++j){
    int idx = j*512 + t, r = idx >> 4, c = idx & 15;
    uint4 v = make_uint4(0,0,0,0);
    if (m0 + r < M) v = A[(size_t)(m0 + r)*16 + c];
    *(uint4*)(As + SW(r, c*8)) = v;
  }
}

__device__ inline void stA_f32(const float* __restrict__ A, ushort* As, int m0, int M, int t){
  const float4* A4 = (const float4*)A;
  #pragma unroll
  for (int j = 0; j < 8; ++j){
    int idx = j*512 + t, r = idx >> 5, c = idx & 31;
    float4 v = make_float4(0.f,0.f,0.f,0.f);
    if (m0 + r < M) v = A4[(size_t)(m0 + r)*32 + c];
    uint2 u; u.x = pack2(v.x, v.y); u.y = pack2(v.z, v.w);
    *(uint2*)(As + SW(r, c*4)) = u;
  }
}

__device__ inline void stB(const uint4* __restrict__ Bt, ushort* Bs, int t){
  #pragma unroll
  for (int j = 0; j < 4; ++j) ((uint4*)Bs)[j*512 + t] = Bt[j*512 + t];
}

// stage one K-half (64 cols) of a B^T matrix into a 16KB LDS tile.
// global row n occupies 16 uint4; half khalf = 8 uint4 (XOR swizzle stays inside the half).
__device__ inline void stB64(const uint4* __restrict__ Bt, ushort* Bs64, int khalf, int t){
  #pragma unroll
  for (int j = 0; j < 2; ++j){
    int idx = j*512 + t;          // 0..1023
    int n = idx >> 3, c = idx & 7;
    ((uint4*)Bs64)[n*8 + c] = Bt[n*16 + khalf*8 + c];
  }
}

__device__ inline void kloop(const ushort* As, const ushort* Bs, int wr, int wc,
                             int l15, int g, f32x4 acc[2][4]){
  #pragma unroll
  for (int kk = 0; kk < 4; ++kk){
    int kb = kk*32 + g*8;
    bf16x8 a0 = *(const bf16x8*)(As + SW(wr*32 + l15,      kb));
    bf16x8 a1 = *(const bf16x8*)(As + SW(wr*32 + 16 + l15, kb));
    #pragma unroll
    for (int ni = 0; ni < 4; ++ni){
      int n = wc*64 + ni*16 + l15;
      bf16x8 b = *(const bf16x8*)(Bs + SW(n, kb));
      acc[0][ni] = MFMA16(a0, b, acc[0][ni]);
      acc[1][ni] = MFMA16(a1, b, acc[1][ni]);
    }
  }
}

// K-half kloop: B in [128][64] swizzled half-tile, A read at kbase offset
__device__ inline void kloop64(const ushort* As, const ushort* Bs64, int kbase,
                               int wr, int wc, int l15, int g, f32x4 acc[2][4]){
  #pragma unroll
  for (int kk = 0; kk < 2; ++kk){
    int kb = kk*32 + g*8;         // 0..63 within half
    bf16x8 a0 = *(const bf16x8*)(As + SW(wr*32 + l15,      kbase + kb));
    bf16x8 a1 = *(const bf16x8*)(As + SW(wr*32 + 16 + l15, kbase + kb));
    #pragma unroll
    for (int ni = 0; ni < 4; ++ni){
      int n = wc*64 + ni*16 + l15;
      bf16x8 b = *(const bf16x8*)(Bs64 + ((n<<6) + (kb ^ ((n&7)<<3))));
      acc[0][ni] = MFMA16(a0, b, acc[0][ni]);
      acc[1][ni] = MFMA16(a1, b, acc[1][ni]);
    }
  }
}

__device__ inline void accStoreF(float* ldsF, f32x4 acc[2][4], int wr, int wc, int l15, int g){
  #pragma unroll
  for (int mi = 0; mi < 2; ++mi)
    #pragma unroll
    for (int ni = 0; ni < 4; ++ni)
      #pragma unroll
      for (int j = 0; j < 4; ++j)
        ldsF[(wr*32 + mi*16 + g*4 + j)*128 + wc*64 + ni*16 + l15] = acc[mi][ni][j];
}

__device__ inline void accStoreBf(ushort* dst, f32x4 acc[2][4], int wr, int wc, int l15, int g){
  #pragma unroll
  for (int mi = 0; mi < 2; ++mi)
    #pragma unroll
    for (int ni = 0; ni < 4; ++ni)
      #pragma unroll
      for (int j = 0; j < 4; ++j)
        dst[(wr*32 + mi*16 + g*4 + j)*128 + wc*64 + ni*16 + l15] =
            (ushort)f2bf(acc[mi][ni][j]);
}

#define MMHEAD \
  __shared__ ushort lds[32768]; \
  ushort* As = lds; ushort* Bs = lds + 16384; \
  float* accumF = (float*)lds; \
  int t = threadIdx.x, m0 = blockIdx.x * 128; \
  int w = t >> 6, l = t & 63, wr = w >> 1, wc = w & 1, l15 = l & 15, g = l >> 4; \
  const f32x4 zz = {0.f, 0.f, 0.f, 0.f}; \
  (void)accumF;

#define ZACC(A) { \
  _Pragma("unroll") for (int mi_ = 0; mi_ < 2; ++mi_) \
    _Pragma("unroll") for (int ni_ = 0; ni_ < 4; ++ni_) A[mi_][ni_] = zz; }

// ---- fused v-side per layer (r7-verbatim):
//  Yp = v_h@Wl_pos, Yn = v_h@Wl_neg   (written to global for k_mm_c)
//  vmid = 0.9*(aggp@Wl_rpos + aggn@Wl_rneg + v_h@wsum_v + blp + bln) + 0.1*relu(vemb)
//  v_h  = relu(omb*vmid + beta*(vmid@Wv + bv) + v_h)     (in-place)
__global__ __launch_bounds__(512) void k_fused_v(
    const uint4* __restrict__ AggP, const uint4* __restrict__ AggN,
    const uint4* __restrict__ Bph, const uint4* __restrict__ Bpl,   // Wl_rpos
    const uint4* __restrict__ Bnh, const uint4* __restrict__ Bnl,   // Wl_rneg
    const uint4* __restrict__ Bfh, const uint4* __restrict__ Bfl,   // wsum_v
    const uint4* __restrict__ Byph, const uint4* __restrict__ Bypl, // Wl_pos
    const uint4* __restrict__ Bynh, const uint4* __restrict__ Bynl, // Wl_neg
    const uint4* __restrict__ Bvh, const uint4* __restrict__ Bvl,   // Wv
    const float* __restrict__ xv, const float* __restrict__ Wve, const float* __restrict__ bve,
    const float* __restrict__ blp, const float* __restrict__ bln, const float* __restrict__ bvv,
    float omb, float beta,
    uint4* __restrict__ Yp, uint4* __restrict__ Yn, float* vh, int M){
  MMHEAD
  f32x4 accM[2][4], accP[2][4], accN[2][4];
  ZACC(accM) ZACC(accP) ZACC(accN)

  // agg_p @ Wl_rpos (hi/lo)
  stA_bf16(AggP, As, m0, M, t); stB(Bph, Bs, t); __syncthreads();
  kloop(As, Bs, wr, wc, l15, g, accM); __syncthreads();
  stB(Bpl, Bs, t); __syncthreads();
  kloop(As, Bs, wr, wc, l15, g, accM); __syncthreads();
  // agg_n @ Wl_rneg
  stA_bf16(AggN, As, m0, M, t); stB(Bnh, Bs, t); __syncthreads();
  kloop(As, Bs, wr, wc, l15, g, accM); __syncthreads();
  stB(Bnl, Bs, t); __syncthreads();
  kloop(As, Bs, wr, wc, l15, g, accM); __syncthreads();
  // v_h resident for 6 B stages
  stA_f32(vh, As, m0, M, t); stB(Bfh, Bs, t); __syncthreads();
  kloop(As, Bs, wr, wc, l15, g, accM); __syncthreads();
  stB(Bfl, Bs, t); __syncthreads();
  kloop(As, Bs, wr, wc, l15, g, accM); __syncthreads();
  stB(Byph, Bs, t); __syncthreads();
  kloop(As, Bs, wr, wc, l15, g, accP); __syncthreads();
  stB(Bypl, Bs, t); __syncthreads();
  kloop(As, Bs, wr, wc, l15, g, accP); __syncthreads();
  stB(Bynh, Bs, t); __syncthreads();
  kloop(As, Bs, wr, wc, l15, g, accN); __syncthreads();
  stB(Bynl, Bs, t); __syncthreads();
  kloop(As, Bs, wr, wc, l15, g, accN);

  // write Yp/Yn through LDS repack
  __syncthreads();
  accStoreBf(lds,         accP, wr, wc, l15, g);
  accStoreBf(lds + 16384, accN, wr, wc, l15, g);
  __syncthreads();
  #pragma unroll
  for (int j = 0; j < 4; ++j){
    int idx = j*512 + t, r = idx >> 4, c = idx & 15;
    if (m0 + r < M){
      Yp[(size_t)(m0 + r)*16 + c] = ((const uint4*)lds)[idx];
      Yn[(size_t)(m0 + r)*16 + c] = ((const uint4*)(lds + 16384))[idx];
    }
  }
  __syncthreads();

  // vmid epilogue: accM -> full f32 tile -> (regs) -> bf16 swizzled As
  accStoreF(accumF, accM, wr, wc, l15, g);
  __syncthreads();
  float4 vreg[8];
  #pragma unroll
  for (int j = 0; j < 8; ++j){
    int idx = j*512 + t, r = idx >> 5, c4 = idx & 31;
    int row = m0 + r;
    float4 o = make_float4(0.f,0.f,0.f,0.f);
    if (row < M){
      float4 a4 = ((const float4*)accumF)[r*32 + c4];
      float4 bp = ((const float4*)blp)[c4];
      float4 bn = ((const float4*)bln)[c4];
      float4 h = relu4(vemb4(xv, Wve, bve, row, c4*4));
      o.x = 0.9f*(a4.x + bp.x + bn.x) + 0.1f*h.x;
      o.y = 0.9f*(a4.y + bp.y + bn.y) + 0.1f*h.y;
      o.z = 0.9f*(a4.z + bp.z + bn.z) + 0.1f*h.z;
      o.w = 0.9f*(a4.w + bp.w + bn.w) + 0.1f*h.w;
    }
    vreg[j] = o;
  }
  __syncthreads();
  #pragma unroll
  for (int j = 0; j < 8; ++j){
    int idx = j*512 + t, r = idx >> 5, c4 = idx & 31;
    uint2 u; u.x = pack2(vreg[j].x, vreg[j].y); u.y = pack2(vreg[j].z, vreg[j].w);
    *(uint2*)(As + SW(r, c4*4)) = u;
  }
  // vmid @ Wv (hi/lo); As holds vmid bf16
  f32x4 accT[2][4];
  ZACC(accT)
  stB(Bvh, Bs, t); __syncthreads();
  kloop(As, Bs, wr, wc, l15, g, accT); __syncthreads();
  stB(Bvl, Bs, t); __syncthreads();
  kloop(As, Bs, wr, wc, l15, g, accT);

  // final v_h update via 32KB half-tiles in Bs (coalesced float4 RMW on vh)
  float* ldsH = (float*)Bs;
  #pragma unroll
  for (int half = 0; half < 2; ++half){
    __syncthreads();   // protect Bs (kloop reads / previous epilogue reads)
    if ((wr >> 1) == half){
      int rbase = (wr & 1)*32;
      #pragma unroll
      for (int mi = 0; mi < 2; ++mi)
        #pragma unroll
        for (int ni = 0; ni < 4; ++ni)
          #pragma unroll
          for (int j = 0; j < 4; ++j)
            ldsH[(rbase + mi*16 + g*4 + j)*128 + wc*64 + ni*16 + l15] = accT[mi][ni][j];
    }
    __syncthreads();
    #pragma unroll
    for (int j = 0; j < 4; ++j){
      int idx = j*512 + t, r2 = idx >> 5, c4 = idx & 31;
      int row = m0 + half*64 + r2;
      if (row >= M) continue;
      float4 a4 = ((const float4*)ldsH)[r2*32 + c4];
      uint2 um = *(const uint2*)(As + SW(half*64 + r2, c4*4));
      float4 bb = ((const float4*)bvv)[c4];
      float4 vo = *(const float4*)(vh + (size_t)row*HH + c4*4);
      float m0f = bf2f(um.x & 0xFFFFu), m1f = bf2f(um.x >> 16);
      float m2f = bf2f(um.y & 0xFFFFu), m3f = bf2f(um.y >> 16);
      float4 o;
      o.x = fmaxf(omb*m0f + beta*(a4.x + bb.x) + vo.x, 0.f);
      o.y = fmaxf(omb*m1f + beta*(a4.y + bb.y) + vo.y, 0.f);
      o.z = fmaxf(omb*m2f + beta*(a4.z + bb.z) + vo.z, 0.f);
      o.w = fmaxf(omb*m3f + beta*(a4.w + bb.w) + vo.w, 0.f);
      *(float4*)(vh + (size_t)row*HH + c4*4) = o;
    }
  }
}

// ---- clause update (in-place c_h), 48KB LDS (3 blocks/CU), B staged in K-halves:
// c_h = relu(0.9*(mean_p(Yp) + mean_n(Yn) + c_h@wsum_c + blp + bln) + 0.1*relu(cemb)) ----
__device__ inline void addrow8(float f[8], uint4 u){
  f[0] += bf2f(u.x & 0xFFFFu); f[1] += bf2f(u.x >> 16);
  f[2] += bf2f(u.y & 0xFFFFu); f[3] += bf2f(u.y >> 16);
  f[4] += bf2f(u.z & 0xFFFFu); f[5] += bf2f(u.z >> 16);
  f[6] += bf2f(u.w & 0xFFFFu); f[7] += bf2f(u.w >> 16);
}

__global__ __launch_bounds__(512) void k_mm_c(const uint4* ch,
    const uint4* __restrict__ Bh, const uint4* __restrict__ Bl,
    const int* __restrict__ ipp, const int* __restrict__ ecp,
    const int* __restrict__ ipn, const int* __restrict__ ecn,
    const uint4* __restrict__ Yp, const uint4* __restrict__ Yn,
    const float* __restrict__ xc, const float* __restrict__ Wc, const float* __restrict__ bc,
    const float* __restrict__ blp, const float* __restrict__ bln,
    uint4* chout){
  __shared__ ushort lds[24576];          // 48 KB -> 3 blocks/CU
  ushort* As = lds;                      // 32 KB A tile, later bf16 result tile
  ushort* Bs = lds + 16384;              // 16 KB B K-half tile
  int t = threadIdx.x, m0 = blockIdx.x * 128;
  int w = t >> 6, l = t & 63, wr = w >> 1, wc = w & 1, l15 = l & 15, g = l >> 4;
  const f32x4 zz = {0.f, 0.f, 0.f, 0.f};
  f32x4 acc[2][4];
  ZACC(acc)
  stA_bf16(ch, As, m0, NCC, t);
  stB64(Bh, Bs, 0, t); __syncthreads();
  kloop64(As, Bs, 0,  wr, wc, l15, g, acc); __syncthreads();
  stB64(Bh, Bs, 1, t); __syncthreads();
  kloop64(As, Bs, 64, wr, wc, l15, g, acc); __syncthreads();
  stB64(Bl, Bs, 0, t); __syncthreads();
  kloop64(As, Bs, 0,  wr, wc, l15, g, acc); __syncthreads();
  stB64(Bl, Bs, 1, t); __syncthreads();
  kloop64(As, Bs, 64, wr, wc, l15, g, acc);
  __syncthreads();                       // all A reads done; overwrite with result (bf16)
  accStoreBf(As, acc, wr, wc, l15, g);   // plain [128][128] bf16
  __syncthreads();

  // phase 3: 16 lanes per row, polarity-interleaved (r7 shape)
  int c16 = t & 15;
  int rg  = t >> 4;            // 0..31
  #pragma unroll
  for (int pass = 0; pass < 4; ++pass){
    int r = pass*32 + rg;
    int row = m0 + r;
    if (row >= NCC) continue;
    float fp[8] = {0,0,0,0,0,0,0,0};
    float fn[8] = {0,0,0,0,0,0,0,0};
    int sp = row ? ipp[row-1] : 0, ePos = ipp[row];
    int sn = row ? ipn[row-1] : 0, eNeg = ipn[row];
    int jp = sp, jn = sn;
    while (jp < ePos && jn < eNeg){
      uint4 up = Yp[(size_t)ecp[jp]*16 + c16];
      uint4 un = Yn[(size_t)ecn[jn]*16 + c16];
      addrow8(fp, up);
      addrow8(fn, un);
      ++jp; ++jn;
    }
    for (; jp < ePos; ++jp) addrow8(fp, Yp[(size_t)ecp[jp]*16 + c16]);
    for (; jn < eNeg; ++jn) addrow8(fn, Yn[(size_t)ecn[jn]*16 + c16]);
    float invp = 1.f / fmaxf((float)(ePos - sp), 1.f);
    float invn = 1.f / fmaxf((float)(eNeg - sn), 1.f);

    uint4 ru = *(const uint4*)(As + r*128 + c16*8);
    float res[8];
    res[0] = bf2f(ru.x & 0xFFFFu); res[1] = bf2f(ru.x >> 16);
    res[2] = bf2f(ru.y & 0xFFFFu); res[3] = bf2f(ru.y >> 16);
    res[4] = bf2f(ru.z & 0xFFFFu); res[5] = bf2f(ru.z >> 16);
    res[6] = bf2f(ru.w & 0xFFFFu); res[7] = bf2f(ru.w >> 16);
    int gi0 = c16*2, gi1 = gi0 + 1;
    float4 wc0 = ((const float4*)Wc)[gi0],  wc1 = ((const float4*)Wc)[gi1];
    float4 bc0 = ((const float4*)bc)[gi0],  bc1 = ((const float4*)bc)[gi1];
    float4 bp0 = ((const float4*)blp)[gi0], bp1 = ((const float4*)blp)[gi1];
    float4 bn0 = ((const float4*)bln)[gi0], bn1 = ((const float4*)bln)[gi1];
    float xcv = xc[row];
    float wcv[8] = {wc0.x,wc0.y,wc0.z,wc0.w, wc1.x,wc1.y,wc1.z,wc1.w};
    float bcv[8] = {bc0.x,bc0.y,bc0.z,bc0.w, bc1.x,bc1.y,bc1.z,bc1.w};
    float bpv[8] = {bp0.x,bp0.y,bp0.z,bp0.w, bp1.x,bp1.y,bp1.z,bp1.w};
    float bnv[8] = {bn0.x,bn0.y,bn0.z,bn0.w, bn1.x,bn1.y,bn1.z,bn1.w};
    float o[8];
    #pragma unroll
    for (int k = 0; k < 8; ++k){
      float h = fmaxf(fmaf(xcv, wcv[k], bcv[k]), 0.f);
      float m = fmaf(fp[k], invp, fn[k]*invn);
      o[k] = fmaxf(0.9f*(m + res[k] + bpv[k] + bnv[k]) + 0.1f*h, 0.f);
    }
    uint4 u;
    u.x = pack2(o[0], o[1]); u.y = pack2(o[2], o[3]);
    u.z = pack2(o[4], o[5]); u.w = pack2(o[6], o[7]);
    chout[(size_t)row*16 + c16] = u;
  }
}

// out[i] = dot(v_h[i,:], W_fin) + b_fin   (one wave per row)
__global__ void k_final(const float* __restrict__ vh, const float* __restrict__ wf,
                        const float* __restrict__ bf, float* __restrict__ out){
  int wid = (blockIdx.x * 256 + threadIdx.x) >> 6;
  if (wid >= NVV) return;
  int lane = threadIdx.x & 63;
  float2 a = *(const float2*)(vh + (size_t)wid*HH + lane*2);
  float2 w = *(const float2*)(wf + lane*2);
  float s = a.x*w.x + a.y*w.y;
  #pragma unroll
  for (int off = 32; off > 0; off >>= 1) s += __shfl_down(s, off);
  if (lane == 0) out[wid] = s + bf[0];
}

// ---------------- orchestration ----------------
extern "C" void kernel_launch(void* const* d_in, const int* in_sizes, int n_in,
                              void* d_out, int out_size, void* d_ws, size_t ws_size,
                              hipStream_t stream) {
  const float* xv  = (const float*)d_in[0];
  const float* xc  = (const float*)d_in[1];
  const int*   ep  = (const int*)d_in[2];
  const int*   en  = (const int*)d_in[3];
  const float* Wve = (const float*)d_in[4];
  const float* bve = (const float*)d_in[5];
  const float* Wce = (const float*)d_in[6];
  const float* bce = (const float*)d_in[7];
  const float* Wl_pos  = (const float*)d_in[8];
  const float* bl_pos  = (const float*)d_in[9];
  const float* Wr_pos  = (const float*)d_in[10];
  const float* Wl_neg  = (const float*)d_in[11];
  const float* bl_neg  = (const float*)d_in[12];
  const float* Wr_neg  = (const float*)d_in[13];
  const float* Wl_rpos = (const float*)d_in[14];
  const float* bl_rpos = (const float*)d_in[15];
  const float* Wr_rpos = (const float*)d_in[16];
  const float* Wl_rneg = (const float*)d_in[17];
  const float* bl_rneg = (const float*)d_in[18];
  const float* Wr_rneg = (const float*)d_in[19];
  const float* Wv  = (const float*)d_in[20];
  const float* bv  = (const float*)d_in[21];
  const float* Wf  = (const float*)d_in[22];
  const float* bf  = (const float*)d_in[23];
  float* out = (float*)d_out;

  size_t off = 0;
  auto alloc = [&](size_t bytes) -> void* {
    void* p = (char*)d_ws + off;
    off = (off + bytes + 255) & ~(size_t)255;
    return p;
  };
  uint*   c_h  = (uint*)  alloc((size_t)NCC*64*sizeof(uint));   // bf16 NCxH
  float*  v_h  = (float*) alloc((size_t)NVV*HH*sizeof(float));  // f32  NVxH
  uint*   U1   = (uint*)  alloc((size_t)NVV*64*sizeof(uint));   // bf16 NVxH (agg_p -> Yp)
  uint*   U2   = (uint*)  alloc((size_t)NVV*64*sizeof(uint));   // bf16 NVxH (agg_n -> Yn)
  ushort* wt   = (ushort*)alloc((size_t)7*LL*2*16384*sizeof(ushort));
  int*   ipc_p = (int*)  alloc((size_t)NCC*sizeof(int));
  int*   ec_p  = (int*)  alloc((size_t)EE*sizeof(int));
  int*   ipc_n = (int*)  alloc((size_t)NCC*sizeof(int));
  int*   ec_n  = (int*)  alloc((size_t)EE*sizeof(int));
  int*   ipv_p = (int*)  alloc((size_t)NVV*sizeof(int));
  int*   ev_p  = (int*)  alloc((size_t)EE*sizeof(int));
  int*   ipv_n = (int*)  alloc((size_t)NVV*sizeof(int));
  int*   ev_n  = (int*)  alloc((size_t)EE*sizeof(int));
  int*   part  = (int*)  alloc(4096);
  if (off > ws_size){
    k_sentinel<<<1, 64, 0, stream>>>(out, (float)(ws_size >> 20));
    return;
  }

  const int TB = 256;
  const int gE  = (EE + TB-1)/TB;
  const int gV  = (NVV*32 + TB-1)/TB;
  const int gC  = (NCC*32 + TB-1)/TB;
  const int gGv = (NVV + 127)/128;   // 782
  const int gGc = (NCC + 127)/128;   // 3282
  const int gWd = (NVV*64 + TB-1)/TB;

  auto wp = [&](int m, int l, int h) -> const uint4* {
    return (const uint4*)(wt + (size_t)((m*LL + l)*2 + h)*16384);
  };

  auto build = [&](const int* dst, const int* pay, int nd, int* ip, int* eo){
    hipMemsetAsync(ip, 0, (size_t)nd*sizeof(int), stream);
    k_counti<<<gE, TB, 0, stream>>>(dst, ip, EE);
    int nb = (nd + 1023)/1024;
    k_scanb<<<nb, TB, 0, stream>>>(ip, ip, part, nd);
    k_scanp<<<1, TB, 0, stream>>>(part, nb);
    k_scana<<<(nd + TB-1)/TB, TB, 0, stream>>>(ip, part, nd);
    k_fill<<<gE, TB, 0, stream>>>(dst, pay, ip, eo, EE);
  };
  build(ep + EE, ep,      NCC, ipc_p, ec_p);
  build(en + EE, en,      NCC, ipc_n, ec_n);
  build(ep,      ep + EE, NVV, ipv_p, ev_p);
  build(en,      en + EE, NVV, ipv_n, ev_n);

  k_prep<<<(7*LL*128*32)/TB, TB, 0, stream>>>(Wl_pos, Wl_neg, Wl_rpos, Wl_rneg, Wv,
                                              Wr_pos, Wr_neg, Wr_rpos, Wr_rneg, wt);

  k_embed_v<<<gV, TB, 0, stream>>>(xv, Wve, bve, v_h);
  k_embed_c<<<gC, TB, 0, stream>>>(xc, Wce, bce, c_h);

  for (int l = 0; l < LL; ++l){
    const size_t bo = (size_t)l*HH;
    double beta_d = log(0.5/(double)(l+1) + 1.0);

    // agg_p/agg_n from OLD c_h
    k_vgather<<<gWd, TB, 0, stream>>>(c_h, ipv_p, ev_p, ipv_n, ev_n, U1, U2);
    // fused v-side: vmid + Y + v_h update (U1/U2: agg in, Y out)
    k_fused_v<<<gGv, 512, 0, stream>>>((const uint4*)U1, (const uint4*)U2,
                                       wp(2,l,0), wp(2,l,1), wp(3,l,0), wp(3,l,1),
                                       wp(6,l,0), wp(6,l,1),
                                       wp(0,l,0), wp(0,l,1), wp(1,l,0), wp(1,l,1),
                                       wp(4,l,0), wp(4,l,1),
                                       xv, Wve, bve, bl_rpos + bo, bl_rneg + bo, bv + bo,
                                       (float)(1.0 - beta_d), (float)beta_d,
                                       (uint4*)U1, (uint4*)U2, v_h, NVV);
    // clause update, in-place c_h
    k_mm_c<<<gGc, 512, 0, stream>>>((const uint4*)c_h, wp(5,l,0), wp(5,l,1),
                                    ipc_p, ec_p, ipc_n, ec_n,
                                    (const uint4*)U1, (const uint4*)U2,
                                    xc, Wce, bce, bl_pos + bo, bl_neg + bo,
                                    (uint4*)c_h);
  }

  k_final<<<gWd, TB, 0, stream>>>(v_h, Wf, bf, out);
}